// Round 5
// baseline (474.654 us; speedup 1.0000x reference)
//
#include <hip/hip_runtime.h>

typedef __bf16 bf16x8 __attribute__((ext_vector_type(8)));
typedef __bf16 bf16x4 __attribute__((ext_vector_type(4)));
typedef __bf16 bf16x2 __attribute__((ext_vector_type(2)));
typedef float  f32x4  __attribute__((ext_vector_type(4)));
typedef float  f32x16 __attribute__((ext_vector_type(16)));
typedef unsigned int uintx4 __attribute__((ext_vector_type(4)));

#define EMB 768
#define HEADS 12
#define HD 64
#define FF 3072
#define SEQ 1024
#define BATCH 8
#define ROWS (BATCH*SEQ)          /* 8192 */
#define QKVSZ ((size_t)BATCH*HEADS*SEQ*HD)   /* 6291456 elements per q/k/v */
#define LOG2E 1.44269504088896f

__device__ __forceinline__ void gload16(const void* g, void* l) {
    __builtin_amdgcn_global_load_lds(
        (const __attribute__((address_space(1))) unsigned int*)g,
        (__attribute__((address_space(3))) unsigned int*)l,
        16, 0, 0);
}

__device__ __forceinline__ unsigned int pkbf16(float lo, float hi) {
    bf16x2 w = { (__bf16)lo, (__bf16)hi };
    return __builtin_bit_cast(unsigned int, w);
}

// ---------------- LayerNorm (fp32 in -> bf16 out) ----------------
__global__ __launch_bounds__(256) void ln_kernel(const float* __restrict__ x,
        const float* __restrict__ g, const float* __restrict__ b,
        __bf16* __restrict__ out)
{
    int row = blockIdx.x;
    int tid = threadIdx.x;
    const float* xr = x + (size_t)row * EMB;
    float v0 = xr[tid], v1 = xr[tid + 256], v2 = xr[tid + 512];
    float s  = v0 + v1 + v2;
    float ss = v0*v0 + v1*v1 + v2*v2;
    #pragma unroll
    for (int off = 32; off >= 1; off >>= 1) {
        s  += __shfl_xor(s, off);
        ss += __shfl_xor(ss, off);
    }
    __shared__ float red[2][4];
    int wave = tid >> 6;
    if ((tid & 63) == 0) { red[0][wave] = s; red[1][wave] = ss; }
    __syncthreads();
    s  = red[0][0] + red[0][1] + red[0][2] + red[0][3];
    ss = red[1][0] + red[1][1] + red[1][2] + red[1][3];
    float mu  = s * (1.0f / EMB);
    float var = ss * (1.0f / EMB) - mu * mu;
    float inv = rsqrtf(var + 1e-5f);
    __bf16* orow = out + (size_t)row * EMB;
    orow[tid]       = (__bf16)((v0 - mu) * inv * g[tid]       + b[tid]);
    orow[tid + 256] = (__bf16)((v1 - mu) * inv * g[tid + 256] + b[tid + 256]);
    orow[tid + 512] = (__bf16)((v2 - mu) * inv * g[tid + 512] + b[tid + 512]);
}

// ---------------- W[K][N] fp32 -> WT[N][K] bf16 ----------------
__global__ __launch_bounds__(256) void transpose_convert(const float* __restrict__ W,
        __bf16* __restrict__ WT, int K, int N)
{
    __shared__ float t[32][33];
    int nb = blockIdx.x * 32, kb = blockIdx.y * 32;
    int tx = threadIdx.x, ty = threadIdx.y;
    #pragma unroll
    for (int i = 0; i < 32; i += 8)
        t[ty + i][tx] = W[(size_t)(kb + ty + i) * N + nb + tx];
    __syncthreads();
    #pragma unroll
    for (int i = 0; i < 32; i += 8)
        WT[(size_t)(nb + ty + i) * K + kb + tx] = (__bf16)t[tx][ty + i];
}

// ============ 256x256 GEMM, 8 waves, BK=64, dbuf LDS + swizzled reads (T2/T3/T5) ============
// C = A[M,K] @ BT[N,K]^T + bias
// EPI 0: qkv split. q scaled by 0.125*log2(e) -> [b,h,s,d]; k -> [b,h,s,d]; v -> vt[b,h,d,s]
// EPI 2: bf16 out = gelu(C + bias)
template<int EPI>
__global__ __launch_bounds__(512) void gemm256(
    const __bf16* __restrict__ A, const __bf16* __restrict__ BT,
    const float* __restrict__ bias, __bf16* __restrict__ vtout,
    void* __restrict__ outp, int M, int N, int K)
{
    extern __shared__ char lds[];   // A0:0 B0:32K A1:64K B1:96K  (128 KiB)
    int tid = threadIdx.x;
    int lane = tid & 63, wid = tid >> 6;
    int wr = wid >> 2, wc = wid & 3;
    int lr = lane & 15, lg = lane >> 4;

    // bijective XCD swizzle (nwg % 8 == 0 for all our shapes)
    int nbx = gridDim.x;
    int nwg = nbx * gridDim.y;
    int orig = blockIdx.y * nbx + blockIdx.x;
    int q8 = nwg >> 3, r8 = nwg & 7;
    int xcd = orig & 7, rest = orig >> 3;
    int swz = (xcd < r8 ? xcd * (q8 + 1) : r8 * (q8 + 1) + (xcd - r8) * q8) + rest;
    int bm = (swz / nbx) * 256;
    int bn = (swz % nbx) * 256;

    // staging map: issue i covers rows [i*64, i*64+64); thread -> linear LDS off i*8192 + tid*16
    int srow = tid >> 3;                       // row within issue block
    int scolb = ((tid & 7) * 16) ^ ((srow & 7) << 4);   // inverse-swizzled source col-byte
    const char* Ag = (const char*)A  + ((size_t)(bm + srow) * K) * 2 + scolb;
    const char* Bg = (const char*)BT + ((size_t)(bn + srow) * K) * 2 + scolb;
    size_t issue_stride = (size_t)64 * K * 2;

#define STAGE256(buf, k0)                                                   \
    do {                                                                    \
        const char* ag_ = Ag + (size_t)(k0) * 2;                            \
        const char* bg_ = Bg + (size_t)(k0) * 2;                            \
        char* la_ = lds + (buf) * 65536 + wid * 1024;                       \
        char* lb_ = la_ + 32768;                                            \
        _Pragma("unroll")                                                   \
        for (int i_ = 0; i_ < 4; i_++)                                      \
            gload16(ag_ + i_ * issue_stride, la_ + i_ * 8192);              \
        _Pragma("unroll")                                                   \
        for (int i_ = 0; i_ < 4; i_++)                                      \
            gload16(bg_ + i_ * issue_stride, lb_ + i_ * 8192);              \
    } while (0)

    // reader offsets: row_local*128 + ((ksub*64 + lg*16) ^ ((lr&7)<<4))
    int sxor = (lr & 7) << 4;
    int koff0 = (lg * 16) ^ sxor;
    int koff1 = (64 + lg * 16) ^ sxor;
    int abase = (wr * 128 + lr) * 128;          // + mi*2048
    int bbase = 32768 + (wc * 64 + lr) * 128;   // + ni*2048

    f32x4 acc[8][4];
    #pragma unroll
    for (int i = 0; i < 8; i++)
        #pragma unroll
        for (int j = 0; j < 4; j++) acc[i][j] = (f32x4){0.f, 0.f, 0.f, 0.f};

    int NT = K >> 6;
    STAGE256(0, 0);
    __syncthreads();
    int cur = 0;
    for (int t = 0; t < NT; ++t) {
        if (t + 1 < NT) STAGE256(cur ^ 1, (t + 1) * 64);
        const char* base = lds + cur * 65536;
        #pragma unroll
        for (int ksub = 0; ksub < 2; ksub++) {
            int ko = ksub ? koff1 : koff0;
            bf16x8 af[8], bfr[4];
            #pragma unroll
            for (int mi = 0; mi < 8; mi++)
                af[mi] = *(const bf16x8*)(base + abase + mi * 2048 + ko);
            #pragma unroll
            for (int ni = 0; ni < 4; ni++)
                bfr[ni] = *(const bf16x8*)(base + bbase + ni * 2048 + ko);
            __builtin_amdgcn_s_setprio(1);
            #pragma unroll
            for (int mi = 0; mi < 8; mi++)
                #pragma unroll
                for (int ni = 0; ni < 4; ni++)
                    acc[mi][ni] = __builtin_amdgcn_mfma_f32_16x16x32_bf16(af[mi], bfr[ni], acc[mi][ni], 0, 0, 0);
            __builtin_amdgcn_s_setprio(0);
        }
        __syncthreads();
        cur ^= 1;
    }
#undef STAGE256

    #pragma unroll
    for (int mi = 0; mi < 8; mi++) {
        int row = bm + wr * 128 + mi * 16 + lg * 4;
        #pragma unroll
        for (int ni = 0; ni < 4; ni++) {
            int col = bn + wc * 64 + ni * 16 + lr;
            float bv = bias[col];
            #pragma unroll
            for (int j = 0; j < 4; j++) {
                int r = row + j;
                float v = acc[mi][ni][j] + bv;
                if (EPI == 0) {
                    int which = col / 768;
                    int cc = col - which * 768;
                    int hh = cc >> 6, dd = cc & 63;
                    int bb = r >> 10, s = r & 1023;
                    if (which == 0) {
                        v *= 0.125f * LOG2E;   // fold 1/sqrt(64) and log2(e) into Q
                        ((__bf16*)outp)[((((size_t)bb * HEADS + hh) << 10) + s) * HD + dd] = (__bf16)v;
                    } else if (which == 1) {
                        ((__bf16*)outp)[QKVSZ + ((((size_t)bb * HEADS + hh) << 10) + s) * HD + dd] = (__bf16)v;
                    } else {
                        vtout[(((size_t)bb * HEADS + hh) * HD + dd) * SEQ + s] = (__bf16)v;
                    }
                } else {
                    float u = 0.7978845608028654f * (v + 0.044715f * v * v * v);
                    float e = __expf(2.0f * u);
                    float th = 1.0f - 2.0f / (e + 1.0f);
                    ((__bf16*)outp)[(size_t)r * N + col] = (__bf16)(0.5f * v * (1.0f + th));
                }
            }
        }
    }
}

// ---------------- GEMM: C = A[M,K] @ BT[N,K]^T + bias + resid (fp32 out), 128x128, m97 ----------------
__global__ __launch_bounds__(256) void gemm_bt(
    const __bf16* __restrict__ A, const __bf16* __restrict__ BT,
    const float* __restrict__ bias, const float* __restrict__ resid,
    float* __restrict__ outp, int M, int N, int K)
{
    __shared__ __bf16 Al[128][32];
    __shared__ __bf16 Bl[128][32];
    int tid  = threadIdx.x;
    int lane = tid & 63, wave = tid >> 6;
    int wr = wave >> 1, wc = wave & 1;
    int lr = lane & 15, lg = lane >> 4;
    int bn = blockIdx.x * 128, bm = blockIdx.y * 128;

    int srow = wave * 16 + (lane >> 2);
    int scol = (lane & 3) * 8;
    const __bf16* Ag0 = A  + (size_t)(bm + srow) * K + scol;
    const __bf16* Ag1 = Ag0 + (size_t)64 * K;
    const __bf16* Bg0 = BT + (size_t)(bn + srow) * K + scol;
    const __bf16* Bg1 = Bg0 + (size_t)64 * K;
    __bf16* lA0 = &Al[wave * 16][0];
    __bf16* lA1 = &Al[64 + wave * 16][0];
    __bf16* lB0 = &Bl[wave * 16][0];
    __bf16* lB1 = &Bl[64 + wave * 16][0];

    f32x4 acc[4][4];
    #pragma unroll
    for (int i = 0; i < 4; i++)
        #pragma unroll
        for (int j = 0; j < 4; j++) acc[i][j] = (f32x4){0.f, 0.f, 0.f, 0.f};

    for (int k0 = 0; k0 < K; k0 += 32) {
        gload16(Ag0 + k0, lA0);
        gload16(Ag1 + k0, lA1);
        gload16(Bg0 + k0, lB0);
        gload16(Bg1 + k0, lB1);
        __syncthreads();
        bf16x8 af[4], bfr[4];
        #pragma unroll
        for (int mi = 0; mi < 4; mi++) af[mi]  = *(const bf16x8*)&Al[wr*64 + mi*16 + lr][lg*8];
        #pragma unroll
        for (int ni = 0; ni < 4; ni++) bfr[ni] = *(const bf16x8*)&Bl[wc*64 + ni*16 + lr][lg*8];
        #pragma unroll
        for (int mi = 0; mi < 4; mi++)
            #pragma unroll
            for (int ni = 0; ni < 4; ni++)
                acc[mi][ni] = __builtin_amdgcn_mfma_f32_16x16x32_bf16(af[mi], bfr[ni], acc[mi][ni], 0, 0, 0);
        __syncthreads();
    }

    #pragma unroll
    for (int mi = 0; mi < 4; mi++) {
        int row = bm + wr*64 + mi*16 + lg*4;
        #pragma unroll
        for (int ni = 0; ni < 4; ni++) {
            int col = bn + wc*64 + ni*16 + lr;
            float bv = bias[col];
            #pragma unroll
            for (int j = 0; j < 4; j++) {
                int r = row + j;
                outp[(size_t)r * N + col] = acc[mi][ni][j] + bv + resid[(size_t)r * N + col];
            }
        }
    }
}

// ---------------- Flash attention: 32x32 MFMA, zero LDS, zero barriers (exp2 domain) ----------------
__device__ __forceinline__ void loadK(bf16x8 (&dst)[8], const __bf16* Kp, int t, int lq, int hi) {
    #pragma unroll
    for (int kb = 0; kb < 2; kb++)
        #pragma unroll
        for (int dc = 0; dc < 4; dc++)
            dst[kb*4+dc] = *(const bf16x8*)(Kp + (size_t)(t*64 + kb*32 + lq) * HD + dc*16 + hi*8);
}

__global__ __launch_bounds__(256) void attn_kernel(
    const __bf16* __restrict__ Q, const __bf16* __restrict__ Km,
    const __bf16* __restrict__ Vt, __bf16* __restrict__ Aout)
{
    int blk = blockIdx.x;                 // grid = B*H*8
    int bh = blk >> 3, qblk = blk & 7;
    int bb = bh / HEADS, hh = bh % HEADS;
    const __bf16* Qp = Q  + (size_t)bh * SEQ * HD;
    const __bf16* Kp = Km + (size_t)bh * SEQ * HD;
    const __bf16* Vp = Vt + (size_t)bh * HD * SEQ;   // [64][1024]
    int lane = threadIdx.x & 63, wave = threadIdx.x >> 6;
    int lq = lane & 31, hi = lane >> 5;
    int q0 = qblk * 128 + wave * 32;

    bf16x8 qf[4];
    #pragma unroll
    for (int dc = 0; dc < 4; dc++)
        qf[dc] = *(const bf16x8*)(Qp + (size_t)(q0 + lq) * HD + dc*16 + hi*8);

    f32x16 o0, o1;
    #pragma unroll
    for (int i = 0; i < 16; i++) { o0[i] = 0.f; o1[i] = 0.f; }
    float m = -1e30f, l = 0.0f;

    bf16x8 kfA[8], kfB[8];
    loadK(kfA, Kp, 0, lq, hi);

#define ATTN_TILE(KF, KFN, T)                                                        \
    do {                                                                             \
        bf16x8 vf[8];                                                                \
        _Pragma("unroll")                                                            \
        for (int nb = 0; nb < 2; nb++)                                               \
            _Pragma("unroll")                                                        \
            for (int ks = 0; ks < 4; ks++)                                           \
                vf[nb*4+ks] = *(const bf16x8*)(Vp + (size_t)(nb*32 + lq) * SEQ       \
                                               + (T)*64 + ks*16 + hi*8);             \
        f32x16 st0, st1;                                                             \
        _Pragma("unroll")                                                            \
        for (int i = 0; i < 16; i++) { st0[i] = 0.f; st1[i] = 0.f; }                 \
        _Pragma("unroll")                                                            \
        for (int dc = 0; dc < 4; dc++)                                               \
            st0 = __builtin_amdgcn_mfma_f32_32x32x16_bf16(KF[dc], qf[dc], st0, 0, 0, 0); \
        _Pragma("unroll")                                                            \
        for (int dc = 0; dc < 4; dc++)                                               \
            st1 = __builtin_amdgcn_mfma_f32_32x32x16_bf16(KF[4+dc], qf[dc], st1, 0, 0, 0); \
        loadK(KFN, Kp, (T)+1, lq, hi);                                               \
        float pmax = st0[0];                                                         \
        _Pragma("unroll")                                                            \
        for (int i = 1; i < 16; i++) pmax = fmaxf(pmax, st0[i]);                     \
        _Pragma("unroll")                                                            \
        for (int i = 0; i < 16; i++) pmax = fmaxf(pmax, st1[i]);                     \
        pmax = fmaxf(pmax, __shfl_xor(pmax, 32));                                    \
        if (__any(pmax > m + 11.5f)) {                                               \
            float mn = fmaxf(m, pmax);                                               \
            float sc = exp2f(m - mn);                                                \
            _Pragma("unroll")                                                        \
            for (int r = 0; r < 16; r++) {                                           \
                float scr = __shfl(sc, (r & 3) + 8*(r >> 2) + 4*hi);                 \
                o0[r] *= scr; o1[r] *= scr;                                          \
            }                                                                        \
            l *= sc; m = mn;                                                         \
        }                                                                            \
        float p[32];                                                                 \
        _Pragma("unroll")                                                            \
        for (int i = 0; i < 16; i++) { p[i] = exp2f(st0[i] - m);                     \
                                       p[16+i] = exp2f(st1[i] - m); }                \
        float ps = 0.f;                                                              \
        _Pragma("unroll")                                                            \
        for (int i = 0; i < 32; i++) ps += p[i];                                     \
        ps += __shfl_xor(ps, 32);                                                    \
        l += ps;                                                                     \
        _Pragma("unroll")                                                            \
        for (int ks = 0; ks < 4; ks++) {                                             \
            unsigned int pa_ = pkbf16(p[ks*8+0], p[ks*8+1]);                         \
            unsigned int pc_ = pkbf16(p[ks*8+2], p[ks*8+3]);                         \
            unsigned int pb_ = pkbf16(p[ks*8+4], p[ks*8+5]);                         \
            unsigned int pd_ = pkbf16(p[ks*8+6], p[ks*8+7]);                         \
            asm("v_permlane32_swap_b32 %0, %1" : "+v"(pb_), "+v"(pa_));              \
            asm("v_permlane32_swap_b32 %0, %1" : "+v"(pd_), "+v"(pc_));              \
            uintx4 w_ = { pa_, pc_, pb_, pd_ };                                      \
            bf16x8 paf = __builtin_bit_cast(bf16x8, w_);                             \
            o0 = __builtin_amdgcn_mfma_f32_32x32x16_bf16(paf, vf[ks],   o0, 0, 0, 0); \
            o1 = __builtin_amdgcn_mfma_f32_32x32x16_bf16(paf, vf[4+ks], o1, 0, 0, 0); \
        }                                                                            \
    } while (0)

    #pragma unroll 1
    for (int t = 0; t < 16; t += 2) {
        ATTN_TILE(kfA, kfB, t);
        ATTN_TILE(kfB, kfA, t + 1);     // last prefetch reads past K (valid: V region follows)
    }
#undef ATTN_TILE

    float linv = 1.0f / l;
    #pragma unroll
    for (int r = 0; r < 16; r++) {
        int crow = (r & 3) + 8*(r >> 2) + 4*hi;
        float sc = __shfl(linv, crow);
        int q = q0 + crow;
        __bf16* dst = Aout + ((size_t)bb * SEQ + q) * EMB + hh * HD + lq;
        dst[0]  = (__bf16)(o0[r] * sc);
        dst[32] = (__bf16)(o1[r] * sc);
    }
}

// ---------------- host side ----------------
extern "C" void kernel_launch(void* const* d_in, const int* in_sizes, int n_in,
                              void* d_out, int out_size, void* d_ws, size_t ws_size,
                              hipStream_t stream) {
    const float* x      = (const float*)d_in[0];
    const float* qkv_w  = (const float*)d_in[1];
    const float* qkv_b  = (const float*)d_in[2];
    const float* out_w  = (const float*)d_in[3];
    const float* out_b  = (const float*)d_in[4];
    const float* ln1_g  = (const float*)d_in[5];
    const float* ln1_b  = (const float*)d_in[6];
    const float* ln2_g  = (const float*)d_in[7];
    const float* ln2_b  = (const float*)d_in[8];
    const float* fc1_w  = (const float*)d_in[9];
    const float* fc1_b  = (const float*)d_in[10];
    const float* fc2_w  = (const float*)d_in[11];
    const float* fc2_b  = (const float*)d_in[12];

    char* ws = (char*)d_ws;
    __bf16* wqkvT  = (__bf16*)(ws + 0);                       // [2304][768]
    __bf16* woutT  = (__bf16*)(ws + 3538944);                 // [768][768]
    __bf16* wfc1T  = (__bf16*)(ws + 4718592);                 // [3072][768]
    __bf16* wfc2T  = (__bf16*)(ws + 9437184);                 // [768][3072]
    float*  x1     = (float*) (ws + 14155776);                // [8192][768] fp32 (written by proj)
    __bf16* vt     = (__bf16*)(ws + 14155776);                // [B*H][64][1024] aliases x1 (dead until proj)
    __bf16* hbuf   = (__bf16*)(ws + 39321600);                // ln out
    __bf16* qbuf   = (__bf16*)(ws + 51904512);                // q,k each 12582912 B (v goes to vt)
    __bf16* attn   = (__bf16*)(ws + 89653248);                // [8192][768]
    __bf16* fc1out = (__bf16*)(ws + 51904512);                // [8192][3072] aliases q/k/attn (dead by then)

    hipFuncSetAttribute((const void*)gemm256<0>, hipFuncAttributeMaxDynamicSharedMemorySize, 131072);
    hipFuncSetAttribute((const void*)gemm256<2>, hipFuncAttributeMaxDynamicSharedMemorySize, 131072);

    // weights -> bf16 transposed
    transpose_convert<<<dim3(2304/32, 768/32),  dim3(32,8), 0, stream>>>(qkv_w, wqkvT, 768, 2304);
    transpose_convert<<<dim3(768/32,  768/32),  dim3(32,8), 0, stream>>>(out_w, woutT, 768, 768);
    transpose_convert<<<dim3(3072/32, 768/32),  dim3(32,8), 0, stream>>>(fc1_w, wfc1T, 768, 3072);
    transpose_convert<<<dim3(768/32,  3072/32), dim3(32,8), 0, stream>>>(fc2_w, wfc2T, 3072, 768);

    // LN1
    ln_kernel<<<ROWS, 256, 0, stream>>>(x, ln1_g, ln1_b, hbuf);
    // QKV: [8192,768] @ [768,2304] (256^2 tiles); v written transposed into vt
    gemm256<0><<<dim3(2304/256, ROWS/256), 512, 131072, stream>>>(hbuf, wqkvT, qkv_b, vt, qbuf, ROWS, 2304, 768);
    // attention (zero-LDS 32x32 path, exp2 domain)
    attn_kernel<<<BATCH*HEADS*(SEQ/128), 256, 0, stream>>>(qbuf, qbuf + QKVSZ, vt, attn);
    // out proj + residual -> x1 (fp32; overwrites vt region only after attn completed)
    gemm_bt<<<dim3(768/128, ROWS/128), 256, 0, stream>>>(attn, woutT, out_b, x, x1, ROWS, 768, 768);
    // LN2
    ln_kernel<<<ROWS, 256, 0, stream>>>(x1, ln2_g, ln2_b, hbuf);
    // FC1 + GELU (256^2 tiles)
    gemm256<2><<<dim3(3072/256, ROWS/256), 512, 131072, stream>>>(hbuf, wfc1T, fc1_b, nullptr, fc1out, ROWS, 3072, 768);
    // FC2 + residual -> d_out (fp32)
    gemm_bt<<<dim3(768/128, ROWS/128), 256, 0, stream>>>(fc1out, wfc2T, fc2_b, x1, (float*)d_out, ROWS, 768, 3072);
}

// Round 6
// 450.739 us; speedup vs baseline: 1.0531x; 1.0531x over previous
//
#include <hip/hip_runtime.h>

typedef __bf16 bf16x8 __attribute__((ext_vector_type(8)));
typedef __bf16 bf16x4 __attribute__((ext_vector_type(4)));
typedef __bf16 bf16x2 __attribute__((ext_vector_type(2)));
typedef float  f32x4  __attribute__((ext_vector_type(4)));
typedef float  f32x16 __attribute__((ext_vector_type(16)));
typedef unsigned int uintx4 __attribute__((ext_vector_type(4)));

#define EMB 768
#define HEADS 12
#define HD 64
#define FF 3072
#define SEQ 1024
#define BATCH 8
#define ROWS (BATCH*SEQ)          /* 8192 */
#define QKVSZ ((size_t)BATCH*HEADS*SEQ*HD)   /* 6291456 elements per q/k/v */
#define LOG2E 1.44269504088896f

__device__ __forceinline__ void gload16(const void* g, void* l) {
    __builtin_amdgcn_global_load_lds(
        (const __attribute__((address_space(1))) unsigned int*)g,
        (__attribute__((address_space(3))) unsigned int*)l,
        16, 0, 0);
}

__device__ __forceinline__ unsigned int pkbf16(float lo, float hi) {
    bf16x2 w = { (__bf16)lo, (__bf16)hi };
    return __builtin_bit_cast(unsigned int, w);
}

// ---------------- LayerNorm (fp32 in -> bf16 out) ----------------
__global__ __launch_bounds__(256) void ln_kernel(const float* __restrict__ x,
        const float* __restrict__ g, const float* __restrict__ b,
        __bf16* __restrict__ out)
{
    int row = blockIdx.x;
    int tid = threadIdx.x;
    const float* xr = x + (size_t)row * EMB;
    float v0 = xr[tid], v1 = xr[tid + 256], v2 = xr[tid + 512];
    float s  = v0 + v1 + v2;
    float ss = v0*v0 + v1*v1 + v2*v2;
    #pragma unroll
    for (int off = 32; off >= 1; off >>= 1) {
        s  += __shfl_xor(s, off);
        ss += __shfl_xor(ss, off);
    }
    __shared__ float red[2][4];
    int wave = tid >> 6;
    if ((tid & 63) == 0) { red[0][wave] = s; red[1][wave] = ss; }
    __syncthreads();
    s  = red[0][0] + red[0][1] + red[0][2] + red[0][3];
    ss = red[1][0] + red[1][1] + red[1][2] + red[1][3];
    float mu  = s * (1.0f / EMB);
    float var = ss * (1.0f / EMB) - mu * mu;
    float inv = rsqrtf(var + 1e-5f);
    __bf16* orow = out + (size_t)row * EMB;
    orow[tid]       = (__bf16)((v0 - mu) * inv * g[tid]       + b[tid]);
    orow[tid + 256] = (__bf16)((v1 - mu) * inv * g[tid + 256] + b[tid + 256]);
    orow[tid + 512] = (__bf16)((v2 - mu) * inv * g[tid + 512] + b[tid + 512]);
}

// ---------------- W[K][N] fp32 -> WT[N][K] bf16 ----------------
__global__ __launch_bounds__(256) void transpose_convert(const float* __restrict__ W,
        __bf16* __restrict__ WT, int K, int N)
{
    __shared__ float t[32][33];
    int nb = blockIdx.x * 32, kb = blockIdx.y * 32;
    int tx = threadIdx.x, ty = threadIdx.y;
    #pragma unroll
    for (int i = 0; i < 32; i += 8)
        t[ty + i][tx] = W[(size_t)(kb + ty + i) * N + nb + tx];
    __syncthreads();
    #pragma unroll
    for (int i = 0; i < 32; i += 8)
        WT[(size_t)(nb + ty + i) * K + kb + tx] = (__bf16)t[tx][ty + i];
}

// ---------------- V [BH][1024][64] bf16 -> Vt [BH][64][1024] bf16 ----------------
__global__ __launch_bounds__(256) void vtrans_kernel(const __bf16* __restrict__ V,
        __bf16* __restrict__ Vt)
{
    __shared__ __bf16 t[64][72];
    int bh = blockIdx.x >> 4, st = blockIdx.x & 15;
    const __bf16* Vp = V + ((size_t)bh * SEQ + st * 64) * HD;
    int r  = threadIdx.x >> 3;
    int c0 = (threadIdx.x & 7) * 8;
    #pragma unroll
    for (int rep = 0; rep < 2; rep++)
        *(bf16x8*)&t[r + rep*32][c0] = *(const bf16x8*)(Vp + (size_t)(r + rep*32) * HD + c0);
    __syncthreads();
    #pragma unroll
    for (int rep = 0; rep < 2; rep++) {
        int dd = r + rep*32;
        bf16x8 o;
        #pragma unroll
        for (int j = 0; j < 8; j++) o[j] = t[c0 + j][dd];
        *(bf16x8*)(Vt + ((size_t)bh * HD + dd) * SEQ + st * 64 + c0) = o;
    }
}

// ---------------- GEMM: C = A[M,K] @ BT[N,K]^T + bias, 128x128 tile, m97 structure ----------------
// EPI 0: qkv split. q scaled 0.125*log2e -> [b,h,s,d]; k -> [b,h,s,d]; v -> [b,h,s,d] (contiguous)
// EPI 1: fp32 out = C + bias + resid
// EPI 2: bf16 out = gelu(C + bias)
template<int EPI>
__global__ __launch_bounds__(256) void gemm_bt(
    const __bf16* __restrict__ A, const __bf16* __restrict__ BT,
    const float* __restrict__ bias, const float* __restrict__ resid,
    void* __restrict__ outp, int M, int N, int K)
{
    __shared__ __bf16 Al[128][32];
    __shared__ __bf16 Bl[128][32];
    int tid  = threadIdx.x;
    int lane = tid & 63, wave = tid >> 6;
    int wr = wave >> 1, wc = wave & 1;
    int lr = lane & 15, lg = lane >> 4;
    int bn = blockIdx.x * 128, bm = blockIdx.y * 128;

    int srow = wave * 16 + (lane >> 2);
    int scol = (lane & 3) * 8;
    const __bf16* Ag0 = A  + (size_t)(bm + srow) * K + scol;
    const __bf16* Ag1 = Ag0 + (size_t)64 * K;
    const __bf16* Bg0 = BT + (size_t)(bn + srow) * K + scol;
    const __bf16* Bg1 = Bg0 + (size_t)64 * K;
    __bf16* lA0 = &Al[wave * 16][0];
    __bf16* lA1 = &Al[64 + wave * 16][0];
    __bf16* lB0 = &Bl[wave * 16][0];
    __bf16* lB1 = &Bl[64 + wave * 16][0];

    f32x4 acc[4][4];
    #pragma unroll
    for (int i = 0; i < 4; i++)
        #pragma unroll
        for (int j = 0; j < 4; j++) acc[i][j] = (f32x4){0.f, 0.f, 0.f, 0.f};

    for (int k0 = 0; k0 < K; k0 += 32) {
        gload16(Ag0 + k0, lA0);
        gload16(Ag1 + k0, lA1);
        gload16(Bg0 + k0, lB0);
        gload16(Bg1 + k0, lB1);
        __syncthreads();
        bf16x8 af[4], bfr[4];
        #pragma unroll
        for (int mi = 0; mi < 4; mi++) af[mi]  = *(const bf16x8*)&Al[wr*64 + mi*16 + lr][lg*8];
        #pragma unroll
        for (int ni = 0; ni < 4; ni++) bfr[ni] = *(const bf16x8*)&Bl[wc*64 + ni*16 + lr][lg*8];
        #pragma unroll
        for (int mi = 0; mi < 4; mi++)
            #pragma unroll
            for (int ni = 0; ni < 4; ni++)
                acc[mi][ni] = __builtin_amdgcn_mfma_f32_16x16x32_bf16(af[mi], bfr[ni], acc[mi][ni], 0, 0, 0);
        __syncthreads();
    }

    #pragma unroll
    for (int mi = 0; mi < 4; mi++) {
        int row = bm + wr*64 + mi*16 + lg*4;
        #pragma unroll
        for (int ni = 0; ni < 4; ni++) {
            int col = bn + wc*64 + ni*16 + lr;
            float bv = bias[col];
            #pragma unroll
            for (int j = 0; j < 4; j++) {
                int r = row + j;
                float v = acc[mi][ni][j] + bv;
                if (EPI == 0) {
                    int which = col / 768;
                    int cc = col - which * 768;
                    int hh = cc >> 6, dd = cc & 63;
                    int bb = r >> 10, s = r & 1023;
                    if (which == 0) v *= 0.125f * LOG2E;   // fold 1/sqrt(64)*log2e into Q
                    ((__bf16*)outp)[(size_t)which * QKVSZ +
                        ((((size_t)bb * HEADS + hh) << 10) + s) * HD + dd] = (__bf16)v;
                } else if (EPI == 1) {
                    ((float*)outp)[(size_t)r * N + col] = v + resid[(size_t)r * N + col];
                } else {
                    float u = 0.7978845608028654f * (v + 0.044715f * v * v * v);
                    float e = __expf(2.0f * u);
                    float th = 1.0f - 2.0f / (e + 1.0f);
                    ((__bf16*)outp)[(size_t)r * N + col] = (__bf16)(0.5f * v * (1.0f + th));
                }
            }
        }
    }
}

// ---------------- Flash attention: 32x32 MFMA, zero LDS, zero barriers (exp2 domain) ----------------
// XCD-aware block remap: all 8 q-blocks of a head land on the same XCD (blockIdx % 8 heuristic),
// so the head's K/V (256 KB) stays resident in that XCD's 4 MB L2.
__device__ __forceinline__ void loadK(bf16x8 (&dst)[8], const __bf16* Kp, int t, int lq, int hi) {
    #pragma unroll
    for (int kb = 0; kb < 2; kb++)
        #pragma unroll
        for (int dc = 0; dc < 4; dc++)
            dst[kb*4+dc] = *(const bf16x8*)(Kp + (size_t)(t*64 + kb*32 + lq) * HD + dc*16 + hi*8);
}

__global__ __launch_bounds__(256) void attn_kernel(
    const __bf16* __restrict__ Q, const __bf16* __restrict__ Km,
    const __bf16* __restrict__ Vt, __bf16* __restrict__ Aout)
{
    int xcd  = blockIdx.x & 7;            // grid = 768 = 8 XCD * 96
    int idx  = blockIdx.x >> 3;           // 0..95
    int bh   = xcd * 12 + (idx % 12);     // 12 heads per XCD, 8 qblocks each
    int qblk = idx / 12;
    int bb = bh / HEADS, hh = bh % HEADS;
    const __bf16* Qp = Q  + (size_t)bh * SEQ * HD;
    const __bf16* Kp = Km + (size_t)bh * SEQ * HD;
    const __bf16* Vp = Vt + (size_t)bh * HD * SEQ;   // [64][1024]
    int lane = threadIdx.x & 63, wave = threadIdx.x >> 6;
    int lq = lane & 31, hi = lane >> 5;
    int q0 = qblk * 128 + wave * 32;

    bf16x8 qf[4];
    #pragma unroll
    for (int dc = 0; dc < 4; dc++)
        qf[dc] = *(const bf16x8*)(Qp + (size_t)(q0 + lq) * HD + dc*16 + hi*8);

    f32x16 o0, o1;
    #pragma unroll
    for (int i = 0; i < 16; i++) { o0[i] = 0.f; o1[i] = 0.f; }
    float m = -1e30f, l = 0.0f;

    bf16x8 kfA[8], kfB[8];
    loadK(kfA, Kp, 0, lq, hi);

#define ATTN_TILE(KF, KFN, T)                                                        \
    do {                                                                             \
        bf16x8 vf[8];                                                                \
        _Pragma("unroll")                                                            \
        for (int nb = 0; nb < 2; nb++)                                               \
            _Pragma("unroll")                                                        \
            for (int ks = 0; ks < 4; ks++)                                           \
                vf[nb*4+ks] = *(const bf16x8*)(Vp + (size_t)(nb*32 + lq) * SEQ       \
                                               + (T)*64 + ks*16 + hi*8);             \
        f32x16 st0, st1;                                                             \
        _Pragma("unroll")                                                            \
        for (int i = 0; i < 16; i++) { st0[i] = 0.f; st1[i] = 0.f; }                 \
        _Pragma("unroll")                                                            \
        for (int dc = 0; dc < 4; dc++)                                               \
            st0 = __builtin_amdgcn_mfma_f32_32x32x16_bf16(KF[dc], qf[dc], st0, 0, 0, 0); \
        _Pragma("unroll")                                                            \
        for (int dc = 0; dc < 4; dc++)                                               \
            st1 = __builtin_amdgcn_mfma_f32_32x32x16_bf16(KF[4+dc], qf[dc], st1, 0, 0, 0); \
        loadK(KFN, Kp, (T)+1, lq, hi);                                               \
        float pmax = st0[0];                                                         \
        _Pragma("unroll")                                                            \
        for (int i = 1; i < 16; i++) pmax = fmaxf(pmax, st0[i]);                     \
        _Pragma("unroll")                                                            \
        for (int i = 0; i < 16; i++) pmax = fmaxf(pmax, st1[i]);                     \
        pmax = fmaxf(pmax, __shfl_xor(pmax, 32));                                    \
        if (__any(pmax > m + 11.5f)) {                                               \
            float mn = fmaxf(m, pmax);                                               \
            float sc = exp2f(m - mn);                                                \
            _Pragma("unroll")                                                        \
            for (int r = 0; r < 16; r++) {                                           \
                float scr = __shfl(sc, (r & 3) + 8*(r >> 2) + 4*hi);                 \
                o0[r] *= scr; o1[r] *= scr;                                          \
            }                                                                        \
            l *= sc; m = mn;                                                         \
        }                                                                            \
        float p[32];                                                                 \
        _Pragma("unroll")                                                            \
        for (int i = 0; i < 16; i++) { p[i] = exp2f(st0[i] - m);                     \
                                       p[16+i] = exp2f(st1[i] - m); }                \
        float ps = 0.f;                                                              \
        _Pragma("unroll")                                                            \
        for (int i = 0; i < 32; i++) ps += p[i];                                     \
        ps += __shfl_xor(ps, 32);                                                    \
        l += ps;                                                                     \
        _Pragma("unroll")                                                            \
        for (int ks = 0; ks < 4; ks++) {                                             \
            unsigned int pa_ = pkbf16(p[ks*8+0], p[ks*8+1]);                         \
            unsigned int pc_ = pkbf16(p[ks*8+2], p[ks*8+3]);                         \
            unsigned int pb_ = pkbf16(p[ks*8+4], p[ks*8+5]);                         \
            unsigned int pd_ = pkbf16(p[ks*8+6], p[ks*8+7]);                         \
            asm("v_permlane32_swap_b32 %0, %1" : "+v"(pb_), "+v"(pa_));              \
            asm("v_permlane32_swap_b32 %0, %1" : "+v"(pd_), "+v"(pc_));              \
            uintx4 w_ = { pa_, pc_, pb_, pd_ };                                      \
            bf16x8 paf = __builtin_bit_cast(bf16x8, w_);                             \
            o0 = __builtin_amdgcn_mfma_f32_32x32x16_bf16(paf, vf[ks],   o0, 0, 0, 0); \
            o1 = __builtin_amdgcn_mfma_f32_32x32x16_bf16(paf, vf[4+ks], o1, 0, 0, 0); \
        }                                                                            \
    } while (0)

    #pragma unroll 1
    for (int t = 0; t < 16; t += 2) {
        ATTN_TILE(kfA, kfB, t);
        ATTN_TILE(kfB, kfA, t + 1);     // last prefetch reads past K (valid: V region follows)
    }
#undef ATTN_TILE

    float linv = 1.0f / l;
    #pragma unroll
    for (int r = 0; r < 16; r++) {
        int crow = (r & 3) + 8*(r >> 2) + 4*hi;
        float sc = __shfl(linv, crow);
        int q = q0 + crow;
        __bf16* dst = Aout + ((size_t)bb * SEQ + q) * EMB + hh * HD + lq;
        dst[0]  = (__bf16)(o0[r] * sc);
        dst[32] = (__bf16)(o1[r] * sc);
    }
}

// ---------------- host side ----------------
extern "C" void kernel_launch(void* const* d_in, const int* in_sizes, int n_in,
                              void* d_out, int out_size, void* d_ws, size_t ws_size,
                              hipStream_t stream) {
    const float* x      = (const float*)d_in[0];
    const float* qkv_w  = (const float*)d_in[1];
    const float* qkv_b  = (const float*)d_in[2];
    const float* out_w  = (const float*)d_in[3];
    const float* out_b  = (const float*)d_in[4];
    const float* ln1_g  = (const float*)d_in[5];
    const float* ln1_b  = (const float*)d_in[6];
    const float* ln2_g  = (const float*)d_in[7];
    const float* ln2_b  = (const float*)d_in[8];
    const float* fc1_w  = (const float*)d_in[9];
    const float* fc1_b  = (const float*)d_in[10];
    const float* fc2_w  = (const float*)d_in[11];
    const float* fc2_b  = (const float*)d_in[12];

    char* ws = (char*)d_ws;
    __bf16* wqkvT  = (__bf16*)(ws + 0);                       // [2304][768]
    __bf16* woutT  = (__bf16*)(ws + 3538944);                 // [768][768]
    __bf16* wfc1T  = (__bf16*)(ws + 4718592);                 // [3072][768]
    __bf16* wfc2T  = (__bf16*)(ws + 9437184);                 // [768][3072]
    float*  x1     = (float*) (ws + 14155776);                // [8192][768] fp32 (written by proj)
    __bf16* vt     = (__bf16*)(ws + 14155776);                // [B*H][64][1024] aliases x1 (dead until proj)
    __bf16* hbuf   = (__bf16*)(ws + 39321600);                // ln out
    __bf16* qbuf   = (__bf16*)(ws + 51904512);                // q,k,v each 12582912 B
    __bf16* attn   = (__bf16*)(ws + 89653248);                // [8192][768]
    __bf16* fc1out = (__bf16*)(ws + 51904512);                // [8192][3072] aliases q/k/v/attn (dead by then)

    // weights -> bf16 transposed
    transpose_convert<<<dim3(2304/32, 768/32),  dim3(32,8), 0, stream>>>(qkv_w, wqkvT, 768, 2304);
    transpose_convert<<<dim3(768/32,  768/32),  dim3(32,8), 0, stream>>>(out_w, woutT, 768, 768);
    transpose_convert<<<dim3(3072/32, 768/32),  dim3(32,8), 0, stream>>>(fc1_w, wfc1T, 768, 3072);
    transpose_convert<<<dim3(768/32,  3072/32), dim3(32,8), 0, stream>>>(fc2_w, wfc2T, 3072, 768);

    // LN1
    ln_kernel<<<ROWS, 256, 0, stream>>>(x, ln1_g, ln1_b, hbuf);
    // QKV: [8192,768] @ [768,2304]; q/k/v all contiguous [b,h,s,d]
    gemm_bt<0><<<dim3(2304/128, ROWS/128), 256, 0, stream>>>(hbuf, wqkvT, qkv_b, nullptr, qbuf, ROWS, 2304, 768);
    // V -> Vt (coalesced LDS transpose)
    vtrans_kernel<<<BATCH*HEADS*(SEQ/64), 256, 0, stream>>>(qbuf + 2*QKVSZ, vt);
    // attention (zero-LDS 32x32 path, exp2 domain, XCD-local K/V)
    attn_kernel<<<BATCH*HEADS*(SEQ/128), 256, 0, stream>>>(qbuf, qbuf + QKVSZ, vt, attn);
    // out proj + residual -> x1 (fp32; overwrites vt region only after attn completed)
    gemm_bt<1><<<dim3(768/128, ROWS/128), 256, 0, stream>>>(attn, woutT, out_b, x, x1, ROWS, 768, 768);
    // LN2
    ln_kernel<<<ROWS, 256, 0, stream>>>(x1, ln2_g, ln2_b, hbuf);
    // FC1 + GELU
    gemm_bt<2><<<dim3(3072/128, ROWS/128), 256, 0, stream>>>(hbuf, wfc1T, fc1_b, nullptr, fc1out, ROWS, 3072, 768);
    // FC2 + residual -> d_out (fp32)
    gemm_bt<1><<<dim3(768/128, ROWS/128), 256, 0, stream>>>(fc1out, wfc2T, fc2_b, x1, (float*)d_out, ROWS, 768, 3072);
}

// Round 7
// 409.354 us; speedup vs baseline: 1.1595x; 1.1011x over previous
//
#include <hip/hip_runtime.h>

typedef __bf16 bf16x8 __attribute__((ext_vector_type(8)));
typedef __bf16 bf16x4 __attribute__((ext_vector_type(4)));
typedef __bf16 bf16x2 __attribute__((ext_vector_type(2)));
typedef float  f32x4  __attribute__((ext_vector_type(4)));
typedef float  f32x16 __attribute__((ext_vector_type(16)));
typedef unsigned int uintx4 __attribute__((ext_vector_type(4)));

#define EMB 768
#define HEADS 12
#define HD 64
#define FF 3072
#define SEQ 1024
#define BATCH 8
#define ROWS (BATCH*SEQ)          /* 8192 */
#define QKVSZ ((size_t)BATCH*HEADS*SEQ*HD)   /* 6291456 elements per q/k/v */
#define LOG2E 1.44269504088896f

__device__ __forceinline__ void gload16(const void* g, void* l) {
    __builtin_amdgcn_global_load_lds(
        (const __attribute__((address_space(1))) unsigned int*)g,
        (__attribute__((address_space(3))) unsigned int*)l,
        16, 0, 0);
}

__device__ __forceinline__ unsigned int pkbf16(float lo, float hi) {
    bf16x2 w = { (__bf16)lo, (__bf16)hi };
    return __builtin_bit_cast(unsigned int, w);
}

// ---------------- LayerNorm (fp32 in -> bf16 out) ----------------
__global__ __launch_bounds__(256) void ln_kernel(const float* __restrict__ x,
        const float* __restrict__ g, const float* __restrict__ b,
        __bf16* __restrict__ out)
{
    int row = blockIdx.x;
    int tid = threadIdx.x;
    const float* xr = x + (size_t)row * EMB;
    float v0 = xr[tid], v1 = xr[tid + 256], v2 = xr[tid + 512];
    float s  = v0 + v1 + v2;
    float ss = v0*v0 + v1*v1 + v2*v2;
    #pragma unroll
    for (int off = 32; off >= 1; off >>= 1) {
        s  += __shfl_xor(s, off);
        ss += __shfl_xor(ss, off);
    }
    __shared__ float red[2][4];
    int wave = tid >> 6;
    if ((tid & 63) == 0) { red[0][wave] = s; red[1][wave] = ss; }
    __syncthreads();
    s  = red[0][0] + red[0][1] + red[0][2] + red[0][3];
    ss = red[1][0] + red[1][1] + red[1][2] + red[1][3];
    float mu  = s * (1.0f / EMB);
    float var = ss * (1.0f / EMB) - mu * mu;
    float inv = rsqrtf(var + 1e-5f);
    __bf16* orow = out + (size_t)row * EMB;
    orow[tid]       = (__bf16)((v0 - mu) * inv * g[tid]       + b[tid]);
    orow[tid + 256] = (__bf16)((v1 - mu) * inv * g[tid + 256] + b[tid + 256]);
    orow[tid + 512] = (__bf16)((v2 - mu) * inv * g[tid + 512] + b[tid + 512]);
}

// ---------------- W[K][N] fp32 -> WT[N][K] bf16 ----------------
__global__ __launch_bounds__(256) void transpose_convert(const float* __restrict__ W,
        __bf16* __restrict__ WT, int K, int N)
{
    __shared__ float t[32][33];
    int nb = blockIdx.x * 32, kb = blockIdx.y * 32;
    int tx = threadIdx.x, ty = threadIdx.y;
    #pragma unroll
    for (int i = 0; i < 32; i += 8)
        t[ty + i][tx] = W[(size_t)(kb + ty + i) * N + nb + tx];
    __syncthreads();
    #pragma unroll
    for (int i = 0; i < 32; i += 8)
        WT[(size_t)(nb + ty + i) * K + kb + tx] = (__bf16)t[tx][ty + i];
}

// ---------------- V [BH][1024][64] bf16 -> Vt [BH][64][1024] bf16 ----------------
__global__ __launch_bounds__(256) void vtrans_kernel(const __bf16* __restrict__ V,
        __bf16* __restrict__ Vt)
{
    __shared__ __bf16 t[64][72];
    int bh = blockIdx.x >> 4, st = blockIdx.x & 15;
    const __bf16* Vp = V + ((size_t)bh * SEQ + st * 64) * HD;
    int r  = threadIdx.x >> 3;
    int c0 = (threadIdx.x & 7) * 8;
    #pragma unroll
    for (int rep = 0; rep < 2; rep++)
        *(bf16x8*)&t[r + rep*32][c0] = *(const bf16x8*)(Vp + (size_t)(r + rep*32) * HD + c0);
    __syncthreads();
    #pragma unroll
    for (int rep = 0; rep < 2; rep++) {
        int dd = r + rep*32;
        bf16x8 o;
        #pragma unroll
        for (int j = 0; j < 8; j++) o[j] = t[c0 + j][dd];
        *(bf16x8*)(Vt + ((size_t)bh * HD + dd) * SEQ + st * 64 + c0) = o;
    }
}

// ======== Pipelined GEMM: C = A[M,K] @ BT[N,K]^T + bias ========
// BM=256 BN=128 BK=64, 8 waves (512 thr), per-wave 64x64 output.
// 3 LDS buffers (48 KB each), stage 2 tiles ahead, counted vmcnt(6) at tile end
// (never drain to 0 in steady state), raw s_barrier + sched_barrier fences.
// XOR-swizzle (row&7)<<4 on 16B slots of 128B rows, inverse-swizzled global source.
// EPI 0: qkv split (q scaled 0.125*log2e); EPI 1: fp32 = C+bias+resid; EPI 2: gelu bf16.
template<int EPI>
__global__ __launch_bounds__(512) void gemm_pipe(
    const __bf16* __restrict__ A, const __bf16* __restrict__ BT,
    const float* __restrict__ bias, const float* __restrict__ resid,
    void* __restrict__ outp, int M, int N, int K)
{
    extern __shared__ char lds[];   // 3 x 49152: per buf A[256][64] (32K) + B[128][64] (16K)
    const int tid = threadIdx.x;
    const int lane = tid & 63, wid = tid >> 6;
    const int wr = wid >> 1, wc = wid & 1;     // 4x2 wave grid
    const int lr = lane & 15, lg = lane >> 4;

    // bijective XCD swizzle (nwg % 8 == 0 for all our grids)
    int nbx = gridDim.x;
    int nwg = nbx * gridDim.y;
    int orig = blockIdx.y * nbx + blockIdx.x;
    int q8 = nwg >> 3;
    int swz = (orig & 7) * q8 + (orig >> 3);
    int bm = (swz / nbx) * 256;
    int bn = (swz % nbx) * 128;

    // staging: 512 threads, row = tid>>3 (64 rows/issue), 16B col slot = tid&7, inverse-swizzled
    const int srow = tid >> 3;
    const int scolb = ((tid & 7) * 16) ^ ((srow & 7) << 4);
    const char* Ag = (const char*)A  + ((size_t)(bm + srow) * K) * 2 + scolb;
    const char* Bg = (const char*)BT + ((size_t)(bn + srow) * K) * 2 + scolb;
    const size_t rstride = (size_t)64 * K * 2;

#define STAGE_P(t)                                                          \
    do {                                                                    \
        char* base_ = lds + ((t) % 3) * 49152;                              \
        size_t kb_ = (size_t)(t) * 128;                                     \
        _Pragma("unroll")                                                   \
        for (int i_ = 0; i_ < 4; i_++)                                      \
            gload16(Ag + i_ * rstride + kb_, base_ + i_ * 8192 + tid * 16); \
        _Pragma("unroll")                                                   \
        for (int i_ = 0; i_ < 2; i_++)                                      \
            gload16(Bg + i_ * rstride + kb_, base_ + 32768 + i_ * 8192 + tid * 16); \
    } while (0)

    // reader: row*128 + ((ksub*64 + lg*16) ^ ((lr&7)<<4))
    const int kxor = (lr & 7) << 4;
    const int abase = (wr * 64 + lr) * 128;            // + mi*2048
    const int bbase = 32768 + (wc * 64 + lr) * 128;    // + ni*2048

    f32x4 acc[4][4];
    #pragma unroll
    for (int i = 0; i < 4; i++)
        #pragma unroll
        for (int j = 0; j < 4; j++) acc[i][j] = (f32x4){0.f, 0.f, 0.f, 0.f};

    const int NT = K >> 6;
    STAGE_P(0);
    STAGE_P(1);
    asm volatile("s_waitcnt vmcnt(6)" ::: "memory");   // tile 0 landed (tile 1 in flight)
    __builtin_amdgcn_s_barrier();
    __builtin_amdgcn_sched_barrier(0);

    for (int t = 0; t < NT; ++t) {
        if (t + 2 < NT) STAGE_P(t + 2);                // into buf[(t+2)%3]: free since tile t-1 done
        const char* base = lds + (t % 3) * 49152;
        #pragma unroll
        for (int ksub = 0; ksub < 2; ++ksub) {
            const int ko = ((ksub ? 64 : 0) + lg * 16) ^ kxor;
            bf16x8 af[4], bfr[4];
            #pragma unroll
            for (int mi = 0; mi < 4; mi++)
                af[mi] = *(const bf16x8*)(base + abase + mi * 2048 + ko);
            #pragma unroll
            for (int ni = 0; ni < 4; ni++)
                bfr[ni] = *(const bf16x8*)(base + bbase + ni * 2048 + ko);
            __builtin_amdgcn_s_setprio(1);
            #pragma unroll
            for (int mi = 0; mi < 4; mi++)
                #pragma unroll
                for (int ni = 0; ni < 4; ni++)
                    acc[mi][ni] = __builtin_amdgcn_mfma_f32_16x16x32_bf16(af[mi], bfr[ni], acc[mi][ni], 0, 0, 0);
            __builtin_amdgcn_s_setprio(0);
        }
        // drain this tile's ds_reads (next iter's gloads overwrite this buffer region at t+3)
        asm volatile("s_waitcnt lgkmcnt(0)" ::: "memory");
        __builtin_amdgcn_sched_barrier(0);
        if (t + 2 < NT) {
            asm volatile("s_waitcnt vmcnt(6)" ::: "memory");   // tile t+1 landed, t+2 in flight
        } else if (t + 1 < NT) {
            asm volatile("s_waitcnt vmcnt(0)" ::: "memory");   // last tile: all landed
        }
        __builtin_amdgcn_s_barrier();
        __builtin_amdgcn_sched_barrier(0);
    }
#undef STAGE_P

    #pragma unroll
    for (int mi = 0; mi < 4; mi++) {
        int row = bm + wr * 64 + mi * 16 + lg * 4;
        #pragma unroll
        for (int ni = 0; ni < 4; ni++) {
            int col = bn + wc * 64 + ni * 16 + lr;
            float bv = bias[col];
            #pragma unroll
            for (int j = 0; j < 4; j++) {
                int r = row + j;
                float v = acc[mi][ni][j] + bv;
                if (EPI == 0) {
                    int which = col / 768;
                    int cc = col - which * 768;
                    int hh = cc >> 6, dd = cc & 63;
                    int bb = r >> 10, s = r & 1023;
                    if (which == 0) v *= 0.125f * LOG2E;   // fold 1/sqrt(64)*log2e into Q
                    ((__bf16*)outp)[(size_t)which * QKVSZ +
                        ((((size_t)bb * HEADS + hh) << 10) + s) * HD + dd] = (__bf16)v;
                } else if (EPI == 1) {
                    ((float*)outp)[(size_t)r * N + col] = v + resid[(size_t)r * N + col];
                } else {
                    float u = 0.7978845608028654f * (v + 0.044715f * v * v * v);
                    float e = __expf(2.0f * u);
                    float th = 1.0f - 2.0f / (e + 1.0f);
                    ((__bf16*)outp)[(size_t)r * N + col] = (__bf16)(0.5f * v * (1.0f + th));
                }
            }
        }
    }
}

// ---------------- Flash attention: 32x32 MFMA, zero LDS, zero barriers (exp2 domain) ----------------
__device__ __forceinline__ void loadK(bf16x8 (&dst)[8], const __bf16* Kp, int t, int lq, int hi) {
    #pragma unroll
    for (int kb = 0; kb < 2; kb++)
        #pragma unroll
        for (int dc = 0; dc < 4; dc++)
            dst[kb*4+dc] = *(const bf16x8*)(Kp + (size_t)(t*64 + kb*32 + lq) * HD + dc*16 + hi*8);
}

__global__ __launch_bounds__(256) void attn_kernel(
    const __bf16* __restrict__ Q, const __bf16* __restrict__ Km,
    const __bf16* __restrict__ Vt, __bf16* __restrict__ Aout)
{
    int xcd  = blockIdx.x & 7;            // grid = 768 = 8 XCD * 96
    int idx  = blockIdx.x >> 3;           // 0..95
    int bh   = xcd * 12 + (idx % 12);     // 12 heads per XCD, 8 qblocks each
    int qblk = idx / 12;
    int bb = bh / HEADS, hh = bh % HEADS;
    const __bf16* Qp = Q  + (size_t)bh * SEQ * HD;
    const __bf16* Kp = Km + (size_t)bh * SEQ * HD;
    const __bf16* Vp = Vt + (size_t)bh * HD * SEQ;   // [64][1024]
    int lane = threadIdx.x & 63, wave = threadIdx.x >> 6;
    int lq = lane & 31, hi = lane >> 5;
    int q0 = qblk * 128 + wave * 32;

    bf16x8 qf[4];
    #pragma unroll
    for (int dc = 0; dc < 4; dc++)
        qf[dc] = *(const bf16x8*)(Qp + (size_t)(q0 + lq) * HD + dc*16 + hi*8);

    f32x16 o0, o1;
    #pragma unroll
    for (int i = 0; i < 16; i++) { o0[i] = 0.f; o1[i] = 0.f; }
    float m = -1e30f, l = 0.0f;

    bf16x8 kfA[8], kfB[8];
    loadK(kfA, Kp, 0, lq, hi);

#define ATTN_TILE(KF, KFN, T)                                                        \
    do {                                                                             \
        bf16x8 vf[8];                                                                \
        _Pragma("unroll")                                                            \
        for (int nb = 0; nb < 2; nb++)                                               \
            _Pragma("unroll")                                                        \
            for (int ks = 0; ks < 4; ks++)                                           \
                vf[nb*4+ks] = *(const bf16x8*)(Vp + (size_t)(nb*32 + lq) * SEQ       \
                                               + (T)*64 + ks*16 + hi*8);             \
        f32x16 st0, st1;                                                             \
        _Pragma("unroll")                                                            \
        for (int i = 0; i < 16; i++) { st0[i] = 0.f; st1[i] = 0.f; }                 \
        _Pragma("unroll")                                                            \
        for (int dc = 0; dc < 4; dc++)                                               \
            st0 = __builtin_amdgcn_mfma_f32_32x32x16_bf16(KF[dc], qf[dc], st0, 0, 0, 0); \
        _Pragma("unroll")                                                            \
        for (int dc = 0; dc < 4; dc++)                                               \
            st1 = __builtin_amdgcn_mfma_f32_32x32x16_bf16(KF[4+dc], qf[dc], st1, 0, 0, 0); \
        loadK(KFN, Kp, (T)+1, lq, hi);                                               \
        float pmax = st0[0];                                                         \
        _Pragma("unroll")                                                            \
        for (int i = 1; i < 16; i++) pmax = fmaxf(pmax, st0[i]);                     \
        _Pragma("unroll")                                                            \
        for (int i = 0; i < 16; i++) pmax = fmaxf(pmax, st1[i]);                     \
        pmax = fmaxf(pmax, __shfl_xor(pmax, 32));                                    \
        if (__any(pmax > m + 11.5f)) {                                               \
            float mn = fmaxf(m, pmax);                                               \
            float sc = exp2f(m - mn);                                                \
            _Pragma("unroll")                                                        \
            for (int r = 0; r < 16; r++) {                                           \
                float scr = __shfl(sc, (r & 3) + 8*(r >> 2) + 4*hi);                 \
                o0[r] *= scr; o1[r] *= scr;                                          \
            }                                                                        \
            l *= sc; m = mn;                                                         \
        }                                                                            \
        float p[32];                                                                 \
        _Pragma("unroll")                                                            \
        for (int i = 0; i < 16; i++) { p[i] = exp2f(st0[i] - m);                     \
                                       p[16+i] = exp2f(st1[i] - m); }                \
        float ps = 0.f;                                                              \
        _Pragma("unroll")                                                            \
        for (int i = 0; i < 32; i++) ps += p[i];                                     \
        ps += __shfl_xor(ps, 32);                                                    \
        l += ps;                                                                     \
        _Pragma("unroll")                                                            \
        for (int ks = 0; ks < 4; ks++) {                                             \
            unsigned int pa_ = pkbf16(p[ks*8+0], p[ks*8+1]);                         \
            unsigned int pc_ = pkbf16(p[ks*8+2], p[ks*8+3]);                         \
            unsigned int pb_ = pkbf16(p[ks*8+4], p[ks*8+5]);                         \
            unsigned int pd_ = pkbf16(p[ks*8+6], p[ks*8+7]);                         \
            asm("v_permlane32_swap_b32 %0, %1" : "+v"(pb_), "+v"(pa_));              \
            asm("v_permlane32_swap_b32 %0, %1" : "+v"(pd_), "+v"(pc_));              \
            uintx4 w_ = { pa_, pc_, pb_, pd_ };                                      \
            bf16x8 paf = __builtin_bit_cast(bf16x8, w_);                             \
            o0 = __builtin_amdgcn_mfma_f32_32x32x16_bf16(paf, vf[ks],   o0, 0, 0, 0); \
            o1 = __builtin_amdgcn_mfma_f32_32x32x16_bf16(paf, vf[4+ks], o1, 0, 0, 0); \
        }                                                                            \
    } while (0)

    #pragma unroll 1
    for (int t = 0; t < 16; t += 2) {
        ATTN_TILE(kfA, kfB, t);
        ATTN_TILE(kfB, kfA, t + 1);     // last prefetch reads past K (valid: V region follows)
    }
#undef ATTN_TILE

    float linv = 1.0f / l;
    #pragma unroll
    for (int r = 0; r < 16; r++) {
        int crow = (r & 3) + 8*(r >> 2) + 4*hi;
        float sc = __shfl(linv, crow);
        int q = q0 + crow;
        __bf16* dst = Aout + ((size_t)bb * SEQ + q) * EMB + hh * HD + lq;
        dst[0]  = (__bf16)(o0[r] * sc);
        dst[32] = (__bf16)(o1[r] * sc);
    }
}

// ---------------- host side ----------------
extern "C" void kernel_launch(void* const* d_in, const int* in_sizes, int n_in,
                              void* d_out, int out_size, void* d_ws, size_t ws_size,
                              hipStream_t stream) {
    const float* x      = (const float*)d_in[0];
    const float* qkv_w  = (const float*)d_in[1];
    const float* qkv_b  = (const float*)d_in[2];
    const float* out_w  = (const float*)d_in[3];
    const float* out_b  = (const float*)d_in[4];
    const float* ln1_g  = (const float*)d_in[5];
    const float* ln1_b  = (const float*)d_in[6];
    const float* ln2_g  = (const float*)d_in[7];
    const float* ln2_b  = (const float*)d_in[8];
    const float* fc1_w  = (const float*)d_in[9];
    const float* fc1_b  = (const float*)d_in[10];
    const float* fc2_w  = (const float*)d_in[11];
    const float* fc2_b  = (const float*)d_in[12];

    char* ws = (char*)d_ws;
    __bf16* wqkvT  = (__bf16*)(ws + 0);                       // [2304][768]
    __bf16* woutT  = (__bf16*)(ws + 3538944);                 // [768][768]
    __bf16* wfc1T  = (__bf16*)(ws + 4718592);                 // [3072][768]
    __bf16* wfc2T  = (__bf16*)(ws + 9437184);                 // [768][3072]
    float*  x1     = (float*) (ws + 14155776);                // [8192][768] fp32 (written by proj)
    __bf16* vt     = (__bf16*)(ws + 14155776);                // [B*H][64][1024] aliases x1 (dead until proj)
    __bf16* hbuf   = (__bf16*)(ws + 39321600);                // ln out
    __bf16* qbuf   = (__bf16*)(ws + 51904512);                // q,k,v each 12582912 B
    __bf16* attn   = (__bf16*)(ws + 89653248);                // [8192][768]
    __bf16* fc1out = (__bf16*)(ws + 51904512);                // [8192][3072] aliases q/k/v/attn (dead by then)

    hipFuncSetAttribute((const void*)gemm_pipe<0>, hipFuncAttributeMaxDynamicSharedMemorySize, 147456);
    hipFuncSetAttribute((const void*)gemm_pipe<1>, hipFuncAttributeMaxDynamicSharedMemorySize, 147456);
    hipFuncSetAttribute((const void*)gemm_pipe<2>, hipFuncAttributeMaxDynamicSharedMemorySize, 147456);

    // weights -> bf16 transposed
    transpose_convert<<<dim3(2304/32, 768/32),  dim3(32,8), 0, stream>>>(qkv_w, wqkvT, 768, 2304);
    transpose_convert<<<dim3(768/32,  768/32),  dim3(32,8), 0, stream>>>(out_w, woutT, 768, 768);
    transpose_convert<<<dim3(3072/32, 768/32),  dim3(32,8), 0, stream>>>(fc1_w, wfc1T, 768, 3072);
    transpose_convert<<<dim3(768/32,  3072/32), dim3(32,8), 0, stream>>>(fc2_w, wfc2T, 3072, 768);

    // LN1
    ln_kernel<<<ROWS, 256, 0, stream>>>(x, ln1_g, ln1_b, hbuf);
    // QKV: [8192,768] @ [768,2304]; q/k/v contiguous [b,h,s,d]
    gemm_pipe<0><<<dim3(2304/128, ROWS/256), 512, 147456, stream>>>(hbuf, wqkvT, qkv_b, nullptr, qbuf, ROWS, 2304, 768);
    // V -> Vt (coalesced LDS transpose)
    vtrans_kernel<<<BATCH*HEADS*(SEQ/64), 256, 0, stream>>>(qbuf + 2*QKVSZ, vt);
    // attention (zero-LDS 32x32 path, exp2 domain, XCD-local K/V)
    attn_kernel<<<BATCH*HEADS*(SEQ/128), 256, 0, stream>>>(qbuf, qbuf + QKVSZ, vt, attn);
    // out proj + residual -> x1 (fp32; overwrites vt region only after attn completed)
    gemm_pipe<1><<<dim3(768/128, ROWS/256), 512, 147456, stream>>>(attn, woutT, out_b, x, x1, ROWS, 768, 768);
    // LN2
    ln_kernel<<<ROWS, 256, 0, stream>>>(x1, ln2_g, ln2_b, hbuf);
    // FC1 + GELU
    gemm_pipe<2><<<dim3(3072/128, ROWS/256), 512, 147456, stream>>>(hbuf, wfc1T, fc1_b, nullptr, fc1out, ROWS, 3072, 768);
    // FC2 + residual -> d_out (fp32)
    gemm_pipe<1><<<dim3(768/128, ROWS/256), 512, 147456, stream>>>(fc1out, wfc2T, fc2_b, x1, (float*)d_out, ROWS, 768, 3072);
}